// Round 6
// baseline (130.102 us; speedup 1.0000x reference)
//
#include <hip/hip_runtime.h>

#define D_DIM 512

__device__ __forceinline__ float flog2(float x) {
    return __builtin_amdgcn_logf(x);   // bare v_log_f32; inputs >= ~4e-6, no denormal wrapper
}

// ---- per-row sums: E[row] = sum_d x*log2(x). One wave per row, 4 rows/block.
__global__ __launch_bounds__(256)
void jsd_entropy_kernel(const float* __restrict__ a,
                        const float* __restrict__ b,
                        float* __restrict__ E, int N, int M) {
    int wave = threadIdx.x >> 6;
    int lane = threadIdx.x & 63;
    int row = blockIdx.x * 4 + wave;
    if (row >= N + M) return;
    const float* src = (row < N) ? (a + (size_t)row * D_DIM)
                                 : (b + (size_t)(row - N) * D_DIM);
    float s = 0.f;
#pragma unroll
    for (int d = lane; d < D_DIM; d += 64) {
        float x = src[d];
        s = fmaf(x, flog2(x), s);
    }
#pragma unroll
    for (int off = 32; off > 0; off >>= 1) s += __shfl_down(s, off, 64);
    if (lane == 0) E[row] = s;
}

// ---- main: out[i,j] = 1 - 0.5*S_ij + 0.5*(Ea[i] + Eb[j]),  S_ij = sum_d t*log2 t
// 64x64 tile, 4x4 microtile: 2 ds_read_b128 per 16 logs (2 B/log LDS traffic --
// the R5 2x2 microtile saturated the per-CU LDS pipe at ~75%). Split-D z=4 keeps
// grid at 1024 blocks = 4 blocks/CU = 16 waves/CU.
constexpr int BN = 64, BM = 64;
constexpr int DK = 32;                 // d per LDS chunk
constexpr int DSPLIT = 128;            // d per block (z = 4)
constexpr int NCHUNK = DSPLIT / DK;
constexpr int RP = 68;                 // row length in [d][row] layout: 64 rows + 4 pad
                                       // (multiple of 4 -> b128-aligned reads)

__global__ __launch_bounds__(256, 4)
void jsd_main_kernel(const float* __restrict__ a, const float* __restrict__ b,
                     const float* __restrict__ Ea, const float* __restrict__ Eb,
                     float* __restrict__ out, int N, int M) {
    __shared__ float As[DK][RP];  // [d][row] transposed staging
    __shared__ float Bs[DK][RP];

    const int tid = threadIdx.x;       // 256 = 16x16
    const int tx = tid & 15, ty = tid >> 4;
    const int rowBase = blockIdx.y * BN;
    const int colBase = blockIdx.x * BM;
    const int dStart  = blockIdx.z * DSPLIT;

    // staging map: idx in [0,512): row = idx>>3 (0..63), q = idx&7 (float4 within 32-d chunk)
    const int r0 = tid >> 3;           // rep0 row (0..31)
    const int q  = tid & 7;            // float4 index
    const float* aRow0 = a + (size_t)(rowBase + r0) * D_DIM + 4 * q;
    const float* aRow1 = aRow0 + (size_t)32 * D_DIM;   // rep1 row = r0+32
    const float* bRow0 = b + (size_t)(colBase + r0) * D_DIM + 4 * q;
    const float* bRow1 = bRow0 + (size_t)32 * D_DIM;

    float acc[4][4] = {};
    float4 pa0, pa1, pb0, pb1;

    pa0 = *(const float4*)(aRow0 + dStart);
    pa1 = *(const float4*)(aRow1 + dStart);
    pb0 = *(const float4*)(bRow0 + dStart);
    pb1 = *(const float4*)(bRow1 + dStart);

    for (int c = 0; c < NCHUNK; ++c) {
        // commit prefetched regs to LDS (transposed scalar writes)
        As[4 * q + 0][r0] = pa0.x; As[4 * q + 1][r0] = pa0.y;
        As[4 * q + 2][r0] = pa0.z; As[4 * q + 3][r0] = pa0.w;
        As[4 * q + 0][r0 + 32] = pa1.x; As[4 * q + 1][r0 + 32] = pa1.y;
        As[4 * q + 2][r0 + 32] = pa1.z; As[4 * q + 3][r0 + 32] = pa1.w;
        Bs[4 * q + 0][r0] = pb0.x; Bs[4 * q + 1][r0] = pb0.y;
        Bs[4 * q + 2][r0] = pb0.z; Bs[4 * q + 3][r0] = pb0.w;
        Bs[4 * q + 0][r0 + 32] = pb1.x; Bs[4 * q + 1][r0 + 32] = pb1.y;
        Bs[4 * q + 2][r0 + 32] = pb1.z; Bs[4 * q + 3][r0 + 32] = pb1.w;
        __syncthreads();

        // issue next chunk's global loads (latency hidden by compute below)
        if (c + 1 < NCHUNK) {
            int dNext = dStart + (c + 1) * DK;
            pa0 = *(const float4*)(aRow0 + dNext);
            pa1 = *(const float4*)(aRow1 + dNext);
            pb0 = *(const float4*)(bRow0 + dNext);
            pb1 = *(const float4*)(bRow1 + dNext);
        }

        // 4x4 microtile: 2 b128 LDS reads feed 16 add/log/fma triplets
#pragma unroll 4
        for (int dk = 0; dk < DK; ++dk) {
            float4 av = *(const float4*)&As[dk][ty * 4];
            float4 bv = *(const float4*)&Bs[dk][tx * 4];
            float ar[4] = {av.x, av.y, av.z, av.w};
            float br[4] = {bv.x, bv.y, bv.z, bv.w};
#pragma unroll
            for (int r = 0; r < 4; ++r)
#pragma unroll
                for (int cc = 0; cc < 4; ++cc) {
                    float t = ar[r] + br[cc];
                    acc[r][cc] = fmaf(t, flog2(t), acc[r][cc]);
                }
        }
        __syncthreads();
    }

    // epilogue: z==0 folds affine term; all z-slices atomicAdd (out pre-zeroed)
    const bool lead = (blockIdx.z == 0);
#pragma unroll
    for (int r = 0; r < 4; ++r) {
        int i = rowBase + ty * 4 + r;
        float ea = lead ? Ea[i] : 0.f;
        float* p = out + (size_t)i * M + colBase + tx * 4;
#pragma unroll
        for (int cc = 0; cc < 4; ++cc) {
            float v = -0.5f * acc[r][cc];
            if (lead) v += 1.0f + 0.5f * (ea + Eb[colBase + tx * 4 + cc]);
            atomicAdd(p + cc, v);
        }
    }
}

extern "C" void kernel_launch(void* const* d_in, const int* in_sizes, int n_in,
                              void* d_out, int out_size, void* d_ws, size_t ws_size,
                              hipStream_t stream) {
    const float* a = (const float*)d_in[0];
    const float* b = (const float*)d_in[1];
    const int N = in_sizes[0] / D_DIM;   // 1024
    const int M = in_sizes[1] / D_DIM;   // 1024
    float* E = (float*)d_ws;             // Ea[0..N), Eb[N..N+M)

    hipMemsetAsync(d_out, 0, (size_t)out_size * sizeof(float), stream);
    jsd_entropy_kernel<<<(N + M + 3) / 4, 256, 0, stream>>>(a, b, E, N, M);

    dim3 grid(M / BM, N / BN, D_DIM / DSPLIT);   // 16 x 16 x 4 = 1024 blocks
    jsd_main_kernel<<<grid, 256, 0, stream>>>(a, b, E, E + N, (float*)d_out, N, M);
}